// Round 1
// baseline (2038.149 us; speedup 1.0000x reference)
//
#include <hip/hip_runtime.h>
#include <stdint.h>

#define NB   4
#define NPTS 2048
#define NROWS (NB * NPTS)   // 8192
#define KNN  64

// ---------- helpers ----------

__device__ __forceinline__ float wave_max(float v) {
#pragma unroll
  for (int o = 32; o >= 1; o >>= 1) v = fmaxf(v, __shfl_xor(v, o));
  return v;
}
__device__ __forceinline__ float wave_sum(float v) {
#pragma unroll
  for (int o = 32; o >= 1; o >>= 1) v += __shfl_xor(v, o);
  return v;
}

// logK[n,m] = -(max(|a|^2 + |b|^2 - 2 a.b, 0) / 0.005f)
// Symmetric in (a,c): products/additions commute exactly, so the lu-phase and
// lv-phase recomputations give bit-identical values.
__device__ __forceinline__ float logk_val(const float4 a, const float4 c) {
  float dot = a.x * c.x + a.y * c.y + a.z * c.z;
  float d   = a.w + c.w - 2.0f * dot;
  d = fmaxf(d, 0.0f);
  return -(d / 0.005f);   // IEEE divide to match reference -C/eps
}
__device__ __forceinline__ float sqdist(const float4 a, const float4 c) {
  float dot = a.x * c.x + a.y * c.y + a.z * c.z;
  float d   = a.w + c.w - 2.0f * dot;
  return fmaxf(d, 0.0f);
}

__device__ __forceinline__ uint32_t rotl32(uint32_t x, uint32_t d) {
  return (x << d) | (x >> (32u - d));
}

// ---------- kernels ----------

// Pack points into float4 (x,y,z,|p|^2), zero potentials.
__global__ __launch_bounds__(256) void init_kernel(
    const float* __restrict__ preds, const float* __restrict__ inputs,
    float4* __restrict__ in4, float4* __restrict__ pr4,
    float* __restrict__ lu, float* __restrict__ lv) {
  int i = blockIdx.x * 256 + threadIdx.x;
  if (i >= NROWS) return;
  float ax = inputs[3 * i], ay = inputs[3 * i + 1], az = inputs[3 * i + 2];
  in4[i] = make_float4(ax, ay, az, ax * ax + ay * ay + az * az);
  float px = preds[3 * i], py = preds[3 * i + 1], pz = preds[3 * i + 2];
  pr4[i] = make_float4(px, py, pz, px * px + py * py + pz * pz);
  lu[i] = 0.0f;
  lv[i] = 0.0f;
}

// One Sinkhorn half-step: pot_out[row] = -log(2048) - LSE_m(logK[row,m] + pot_in[m])
// Used for both lu (rows=inputs, cols=preds, pot_in=lv) and lv (swapped).
__global__ __launch_bounds__(256) void sink_phase(
    const float4* __restrict__ row_pts, const float4* __restrict__ col_pts,
    const float* __restrict__ pot_in, float* __restrict__ pot_out) {
  __shared__ float smx[4], sms[4];
  int row  = blockIdx.x;            // 0..8191
  int base = (row >> 11) << 11;     // batch offset
  int tid  = threadIdx.x;
  float4 a = row_pts[row];
  const float4* cp = col_pts + base;
  const float*  pi = pot_in + base;

  float xv[8];
  float mx = -INFINITY;
#pragma unroll
  for (int t = 0; t < 8; ++t) {
    int m = tid + (t << 8);
    float x = logk_val(a, cp[m]) + pi[m];
    xv[t] = x;
    mx = fmaxf(mx, x);
  }
  mx = wave_max(mx);
  if ((tid & 63) == 0) smx[tid >> 6] = mx;
  __syncthreads();
  mx = fmaxf(fmaxf(smx[0], smx[1]), fmaxf(smx[2], smx[3]));

  float s = 0.0f;
#pragma unroll
  for (int t = 0; t < 8; ++t) s += expf(xv[t] - mx);
  s = wave_sum(s);
  if ((tid & 63) == 0) sms[tid >> 6] = s;
  __syncthreads();
  if (tid == 0) {
    s = (sms[0] + sms[1]) + (sms[2] + sms[3]);
    pot_out[row] = -logf(2048.0f) - (logf(s) + mx);
  }
}

// assignment[n] = argmax_m (logK + lu[n] + lv[m]); first index wins ties.
// Writes permuted_preds[row] = preds[argmax].
__global__ __launch_bounds__(256) void assign_kernel(
    const float4* __restrict__ in4, const float4* __restrict__ pr4,
    const float* __restrict__ lu, const float* __restrict__ lv,
    float4* __restrict__ perm4) {
  __shared__ unsigned long long smp[4];
  int row  = blockIdx.x;
  int base = (row >> 11) << 11;
  int tid  = threadIdx.x;
  float4 a  = in4[row];
  float lun = lu[row];
  unsigned long long best = 0ull;
#pragma unroll
  for (int t = 0; t < 8; ++t) {
    int m = tid + (t << 8);
    float x = (logk_val(a, pr4[base + m]) + lun) + lv[base + m];
    uint32_t u = __float_as_uint(x);
    u = (u & 0x80000000u) ? ~u : (u | 0x80000000u);   // order-preserving map
    unsigned long long p =
        ((unsigned long long)u << 32) | (uint32_t)(2047 - m);  // ties -> min m
    best = (p > best) ? p : best;
  }
#pragma unroll
  for (int o = 32; o >= 1; o >>= 1) {
    unsigned long long ob = __shfl_xor(best, o);
    best = (ob > best) ? ob : best;
  }
  if ((tid & 63) == 0) smp[tid >> 6] = best;
  __syncthreads();
  if (tid == 0) {
    unsigned long long b0 = smp[0] > smp[1] ? smp[0] : smp[1];
    unsigned long long b1 = smp[2] > smp[3] ? smp[2] : smp[3];
    best = b0 > b1 ? b0 : b1;
    int m = 2047 - (int)(best & 0xFFFFFFFFu);
    perm4[row] = pr4[base + m];
  }
}

// Per row: top-65 NN (self first, dropped), threefry mask, masked avg dist, atomic sum.
__global__ __launch_bounds__(64) void knn_loss_kernel(
    const float4* __restrict__ in4, const float4* __restrict__ perm4,
    float* __restrict__ out) {
  int row  = blockIdx.x;
  int base = (row >> 11) << 11;
  int lane = threadIdx.x;   // 0..63
  float4 a = in4[row];
  const float4* ip = in4 + base;

  float dv[32];
#pragma unroll
  for (int t = 0; t < 32; ++t) dv[t] = sqdist(a, ip[(t << 6) | lane]);

  // local argmin (static indices only)
  float lmv = dv[0];
  int   lmj = lane;
#pragma unroll
  for (int t = 1; t < 32; ++t) {
    float v = dv[t];
    if (v < lmv) { lmv = v; lmj = (t << 6) | lane; }
  }

  float kd = 0.0f;
  int   ki = 0;
  for (int r = 0; r < 65; ++r) {
    // wave argmin with min-index tie-break
    float gv = lmv;
    int   gj = lmj;
#pragma unroll
    for (int o = 1; o < 64; o <<= 1) {
      float ov = __shfl_xor(gv, o);
      int   oj = __shfl_xor(gj, o);
      if (ov < gv || (ov == gv && oj < gj)) { gv = ov; gj = oj; }
    }
    if (r >= 1 && lane == (r - 1)) { kd = gv; ki = gj; }
    // remove winner from its owner lane (static reg indices, predicated)
    bool own = ((gj & 63) == lane);
    int  gs  = gj >> 6;
#pragma unroll
    for (int t = 0; t < 32; ++t)
      if (own && t == gs) dv[t] = INFINITY;
    // rescan local argmin
    lmv = dv[0];
    lmj = lane;
#pragma unroll
    for (int t = 1; t < 32; ++t) {
      float v = dv[t];
      if (v < lmv) { lmv = v; lmj = (t << 6) | lane; }
    }
  }

  // prob (match reference float32 op order/rounding)
  const float C1 = (float)(0.05 * 0.05);             // INV_SCALE**2
  const float C2 = (float)(2.0 * (0.5657 * 0.5657)); // 2*PDF_STD**2
  const float C3 = (float)(0.5657 * 2.5066282746);   // PDF_STD*SQRT_2PI
  float t2 = (kd / C1) / C2;
  float p  = expf(-t2) / C3;

  // jax.random.uniform(key(42), (4,2048,64)) : threefry2x32, bit-exact
  uint32_t gid = ((uint32_t)row << 6) | (uint32_t)lane;  // flat index
  const uint32_t HALF = 262144u;                         // 524288/2
  bool lo = gid < HALF;
  uint32_t c0 = lo ? gid : (gid - HALF);
  uint32_t c1 = lo ? (gid + HALF) : gid;
  const uint32_t k0 = 0u, k1 = 42u;
  const uint32_t k2 = 0x1BD11BDAu ^ k0 ^ k1;
  uint32_t x0 = c0 + k0, x1 = c1 + k1;
#define TF_RND(rr) { x0 += x1; x1 = rotl32(x1, rr); x1 ^= x0; }
  TF_RND(13) TF_RND(15) TF_RND(26) TF_RND(6)
  x0 += k1; x1 += k2 + 1u;
  TF_RND(17) TF_RND(29) TF_RND(16) TF_RND(24)
  x0 += k2; x1 += k0 + 2u;
  TF_RND(13) TF_RND(15) TF_RND(26) TF_RND(6)
  x0 += k0; x1 += k1 + 3u;
  TF_RND(17) TF_RND(29) TF_RND(16) TF_RND(24)
  x0 += k1; x1 += k2 + 4u;
  TF_RND(13) TF_RND(15) TF_RND(26) TF_RND(6)
  x0 += k2; x1 += k0 + 5u;
#undef TF_RND
  uint32_t bits = lo ? x0 : x1;
  float u = __uint_as_float((bits >> 9) | 0x3F800000u) - 1.0f;

  bool msk = (u < p);
  unsigned long long bal = __ballot(msk);
  int cnt = __popcll(bal);
  if (cnt == 0 && lane == KNN - 1) msk = true;  // farthest fallback
  float num = (cnt == 0) ? 1.0f : (float)cnt;

  float4 nb = ip[ki];
  float4 pp = perm4[row];
  float dx = pp.x - nb.x, dy = pp.y - nb.y, dz = pp.z - nb.z;
  float dist = dx * dx + dy * dy + dz * dz;
  float contrib = msk ? dist : 0.0f;
  contrib = wave_sum(contrib);
  if (lane == 0) atomicAdd(out, contrib / num);
}

// ---------- launch ----------

extern "C" void kernel_launch(void* const* d_in, const int* in_sizes, int n_in,
                              void* d_out, int out_size, void* d_ws, size_t ws_size,
                              hipStream_t stream) {
  const float* preds  = (const float*)d_in[0];
  const float* inputs = (const float*)d_in[1];
  float* out = (float*)d_out;

  char* ws = (char*)d_ws;
  float4* in4   = (float4*)(ws);             // 8192*16 = 131072 B
  float4* pr4   = (float4*)(ws + 131072);    // 131072 B
  float*  lu    = (float*)(ws + 262144);     // 32768 B
  float*  lv    = (float*)(ws + 294912);     // 32768 B
  float4* perm4 = (float4*)(ws + 327680);    // 131072 B  (total 448 KiB)

  hipMemsetAsync(d_out, 0, (size_t)out_size * sizeof(float), stream);

  init_kernel<<<(NROWS + 255) / 256, 256, 0, stream>>>(preds, inputs, in4, pr4, lu, lv);

  for (int it = 0; it < 50; ++it) {
    sink_phase<<<NROWS, 256, 0, stream>>>(in4, pr4, lv, lu);  // lu update
    sink_phase<<<NROWS, 256, 0, stream>>>(pr4, in4, lu, lv);  // lv update
  }

  assign_kernel<<<NROWS, 256, 0, stream>>>(in4, pr4, lu, lv, perm4);
  knn_loss_kernel<<<NROWS, 64, 0, stream>>>(in4, perm4, out);
}

// Round 2
// 1390.123 us; speedup vs baseline: 1.4662x; 1.4662x over previous
//
#include <hip/hip_runtime.h>
#include <stdint.h>

#define NB   4
#define NPTS 2048
#define NROWS (NB * NPTS)   // 8192
#define KNN  64
typedef unsigned long long u64;

// ---------- helpers ----------

__device__ __forceinline__ float wave_max(float v) {
#pragma unroll
  for (int o = 32; o >= 1; o >>= 1) v = fmaxf(v, __shfl_xor(v, o));
  return v;
}
__device__ __forceinline__ float wave_sum(float v) {
#pragma unroll
  for (int o = 32; o >= 1; o >>= 1) v += __shfl_xor(v, o);
  return v;
}
__device__ __forceinline__ int wave_sum_i(int v) {
#pragma unroll
  for (int o = 32; o >= 1; o >>= 1) v += __shfl_xor(v, o);
  return v;
}

// raw hardware exp2 / log2 (1-ulp-ish; only used inside Sinkhorn where the
// output dependence is a discrete argmax with gap >> noise)
__device__ __forceinline__ float fexp2(float x) {
  float r; asm("v_exp_f32 %0, %1" : "=v"(r) : "v"(x)); return r;
}
__device__ __forceinline__ float flog2(float x) {
  float r; asm("v_log_f32 %0, %1" : "=v"(r) : "v"(x)); return r;
}

__device__ __forceinline__ float sqdist(const float4 a, const float4 c) {
  float dot = a.x * c.x + a.y * c.y + a.z * c.z;
  float d   = a.w + c.w - 2.0f * dot;
  return fmaxf(d, 0.0f);
}

__device__ __forceinline__ uint32_t rotl32(uint32_t x, uint32_t d) {
  return (x << d) | (x >> (32u - d));
}

// -200 * log2(e): Sinkhorn runs in base-2 scaled domain (pot2 = pot*log2e).
#define NEG_SCALE_L2E (-288.53900817779268f)

// ---------- kernels ----------

__global__ __launch_bounds__(256) void init_kernel(
    const float* __restrict__ preds, const float* __restrict__ inputs,
    float4* __restrict__ in4, float4* __restrict__ pr4,
    float* __restrict__ lu, float* __restrict__ lv) {
  int i = blockIdx.x * 256 + threadIdx.x;
  if (i >= NROWS) return;
  float ax = inputs[3 * i], ay = inputs[3 * i + 1], az = inputs[3 * i + 2];
  in4[i] = make_float4(ax, ay, az, ax * ax + ay * ay + az * az);
  float px = preds[3 * i], py = preds[3 * i + 1], pz = preds[3 * i + 2];
  pr4[i] = make_float4(px, py, pz, px * px + py * py + pz * pz);
  lu[i] = 0.0f;
  lv[i] = 0.0f;
}

// One Sinkhorn half-step in base-2 domain, one wave per row:
// pot2_out[row] = -11 - log2( sum_m exp2(y_m - mx) ) - mx,
// y_m = fma(max(d_nm,0), -200*log2e, pot2_in[m]).
__global__ __launch_bounds__(256) void sink_phase(
    const float4* __restrict__ row_pts, const float4* __restrict__ col_pts,
    const float* __restrict__ pot_in, float* __restrict__ pot_out) {
  int wid  = threadIdx.x >> 6, lane = threadIdx.x & 63;
  int row  = blockIdx.x * 4 + wid;
  int base = row & ~(NPTS - 1);
  float4 a = row_pts[row];
  const float4* cp = col_pts + base;
  const float*  pi = pot_in + base;

  float y[32];
  float m0 = -INFINITY, m1 = -INFINITY, m2 = -INFINITY, m3 = -INFINITY;
#pragma unroll
  for (int t = 0; t < 32; t += 4) {
#pragma unroll
    for (int q = 0; q < 4; ++q) {
      int m = ((t + q) << 6) | lane;
      float4 c = cp[m];
      float dot = a.x * c.x + a.y * c.y + a.z * c.z;
      float d   = fmaxf(a.w + c.w - 2.0f * dot, 0.0f);
      y[t + q]  = fmaf(d, NEG_SCALE_L2E, pi[m]);
    }
    m0 = fmaxf(m0, y[t]);     m1 = fmaxf(m1, y[t + 1]);
    m2 = fmaxf(m2, y[t + 2]); m3 = fmaxf(m3, y[t + 3]);
  }
  float mx = wave_max(fmaxf(fmaxf(m0, m1), fmaxf(m2, m3)));

  float s0 = 0.f, s1 = 0.f, s2 = 0.f, s3 = 0.f;
#pragma unroll
  for (int t = 0; t < 32; t += 4) {
    s0 += fexp2(y[t] - mx);     s1 += fexp2(y[t + 1] - mx);
    s2 += fexp2(y[t + 2] - mx); s3 += fexp2(y[t + 3] - mx);
  }
  float s = wave_sum((s0 + s1) + (s2 + s3));
  if (lane == 0) pot_out[row] = -11.0f - (flog2(s) + mx);
}

// argmax_m (logK2 + lu2[n] + lv2[m]); first index wins ties. One wave per row.
__global__ __launch_bounds__(256) void assign_kernel(
    const float4* __restrict__ in4, const float4* __restrict__ pr4,
    const float* __restrict__ lu, const float* __restrict__ lv,
    float4* __restrict__ perm4) {
  int wid  = threadIdx.x >> 6, lane = threadIdx.x & 63;
  int row  = blockIdx.x * 4 + wid;
  int base = row & ~(NPTS - 1);
  float4 a  = in4[row];
  float lun = lu[row];
  u64 best = 0ull;
#pragma unroll
  for (int t = 0; t < 32; ++t) {
    int m = (t << 6) | lane;
    float4 c = pr4[base + m];
    float dot = a.x * c.x + a.y * c.y + a.z * c.z;
    float d   = fmaxf(a.w + c.w - 2.0f * dot, 0.0f);
    float x   = fmaf(d, NEG_SCALE_L2E, lv[base + m]) + lun;
    uint32_t u = __float_as_uint(x);
    u = (u & 0x80000000u) ? ~u : (u | 0x80000000u);   // order-preserving map
    u64 p = ((u64)u << 32) | (uint32_t)(2047 - m);    // ties -> min m
    best = (p > best) ? p : best;
  }
#pragma unroll
  for (int o = 32; o >= 1; o >>= 1) {
    u64 ob = __shfl_xor(best, o);
    best = (ob > best) ? ob : best;
  }
  if (lane == 0) {
    int m = 2047 - (int)(best & 0xFFFFFFFFu);
    perm4[row] = pr4[base + m];
  }
}

// Per row (one wave, 4 waves/block): exact top-65 via bit-pattern binary
// search + candidate ranking; then threefry mask + masked avg dist.
__global__ __launch_bounds__(256) void knn_loss_kernel(
    const float4* __restrict__ in4, const float4* __restrict__ perm4,
    float* __restrict__ out) {
  __shared__ u64 cand[4][96];
  __shared__ u64 sel[4][64];
  int wid  = threadIdx.x >> 6, lane = threadIdx.x & 63;
  int row  = blockIdx.x * 4 + wid;
  int base = row & ~(NPTS - 1);
  float4 a = in4[row];
  const float4* ip = in4 + base;

  // distances as monotone uint bit patterns (all >= 0)
  uint32_t dvb[32];
#pragma unroll
  for (int t = 0; t < 32; ++t)
    dvb[t] = __float_as_uint(sqdist(a, ip[(t << 6) | lane]));

  // binary search for the 65th-smallest bit pattern T
  uint32_t lo = 0u, hi = 0x7F7FFFFFu;
  while (lo < hi) {
    uint32_t mid = lo + ((hi - lo) >> 1);
    int c = 0;
#pragma unroll
    for (int t = 0; t < 32; ++t) c += (dvb[t] <= mid) ? 1 : 0;
    c = wave_sum_i(c);
    if (c >= 65) hi = mid; else lo = mid + 1;
  }
  uint32_t T = hi;

  // compact candidates (bits <= T) into LDS via shuffle exclusive scan
  int myc = 0;
#pragma unroll
  for (int t = 0; t < 32; ++t) myc += (dvb[t] <= T) ? 1 : 0;
  int inc = myc;
#pragma unroll
  for (int o = 1; o < 64; o <<= 1) {
    int n = __shfl_up(inc, o);
    if (lane >= o) inc += n;
  }
  int off = inc - myc;
  int nc  = __shfl(inc, 63);
  nc = nc < 96 ? nc : 96;
  int p = off;
#pragma unroll
  for (int t = 0; t < 32; ++t) {
    if (dvb[t] <= T) {
      if (p < 96) cand[wid][p] = ((u64)dvb[t] << 32) | (uint32_t)((t << 6) | lane);
      ++p;
    }
  }

  // rank candidates by (bits, idx); ranks 1..64 -> knn positions 0..63
  u64 mine0 = (lane < nc) ? cand[wid][lane] : ~0ull;
  u64 mine1 = (lane + 64 < nc) ? cand[wid][lane + 64] : ~0ull;
  int r0 = 0, r1 = 0;
  for (int j = 0; j < nc; ++j) {
    u64 cj = cand[wid][j];
    r0 += (cj < mine0) ? 1 : 0;
    r1 += (cj < mine1) ? 1 : 0;
  }
  if (lane < nc && r0 >= 1 && r0 <= 64) sel[wid][r0 - 1] = mine0;
  if (lane + 64 < nc && r1 >= 1 && r1 <= 64) sel[wid][r1 - 1] = mine1;
  u64 s = sel[wid][lane];
  float kd = __uint_as_float((uint32_t)(s >> 32));
  int   ki = (int)(s & 0xFFFFFFFFu);

  // prob (bit-exact float32 op order vs reference)
  const float C1 = (float)(0.05 * 0.05);             // INV_SCALE**2
  const float C2 = (float)(2.0 * (0.5657 * 0.5657)); // 2*PDF_STD**2
  const float C3 = (float)(0.5657 * 2.5066282746);   // PDF_STD*SQRT_2PI
  float t2 = (kd / C1) / C2;
  float pr = expf(-t2) / C3;

  // jax.random.uniform(key(42), (4,2048,64)) : threefry2x32, bit-exact
  uint32_t gid = ((uint32_t)row << 6) | (uint32_t)lane;
  const uint32_t HALF = 262144u;
  bool lo2 = gid < HALF;
  uint32_t c0 = lo2 ? gid : (gid - HALF);
  uint32_t c1 = lo2 ? (gid + HALF) : gid;
  const uint32_t k0 = 0u, k1 = 42u;
  const uint32_t k2 = 0x1BD11BDAu ^ k0 ^ k1;
  uint32_t x0 = c0 + k0, x1 = c1 + k1;
#define TF_RND(rr) { x0 += x1; x1 = rotl32(x1, rr); x1 ^= x0; }
  TF_RND(13) TF_RND(15) TF_RND(26) TF_RND(6)
  x0 += k1; x1 += k2 + 1u;
  TF_RND(17) TF_RND(29) TF_RND(16) TF_RND(24)
  x0 += k2; x1 += k0 + 2u;
  TF_RND(13) TF_RND(15) TF_RND(26) TF_RND(6)
  x0 += k0; x1 += k1 + 3u;
  TF_RND(17) TF_RND(29) TF_RND(16) TF_RND(24)
  x0 += k1; x1 += k2 + 4u;
  TF_RND(13) TF_RND(15) TF_RND(26) TF_RND(6)
  x0 += k2; x1 += k0 + 5u;
#undef TF_RND
  uint32_t bits = lo2 ? x0 : x1;
  float u = __uint_as_float((bits >> 9) | 0x3F800000u) - 1.0f;

  bool msk = (u < pr);
  u64 bal = __ballot(msk);
  int cnt = __popcll(bal);
  if (cnt == 0 && lane == KNN - 1) msk = true;  // farthest fallback
  float num = (cnt == 0) ? 1.0f : (float)cnt;

  float4 nb = ip[ki];
  float4 pp = perm4[row];
  float dx = pp.x - nb.x, dy = pp.y - nb.y, dz = pp.z - nb.z;
  float dist = dx * dx + dy * dy + dz * dz;
  float contrib = msk ? dist : 0.0f;
  contrib = wave_sum(contrib);
  if (lane == 0) atomicAdd(out, contrib / num);
}

// ---------- launch ----------

extern "C" void kernel_launch(void* const* d_in, const int* in_sizes, int n_in,
                              void* d_out, int out_size, void* d_ws, size_t ws_size,
                              hipStream_t stream) {
  const float* preds  = (const float*)d_in[0];
  const float* inputs = (const float*)d_in[1];
  float* out = (float*)d_out;

  char* ws = (char*)d_ws;
  float4* in4   = (float4*)(ws);             // 131072 B
  float4* pr4   = (float4*)(ws + 131072);    // 131072 B
  float*  lu    = (float*)(ws + 262144);     // 32768 B (base-2 scaled)
  float*  lv    = (float*)(ws + 294912);     // 32768 B (base-2 scaled)
  float4* perm4 = (float4*)(ws + 327680);    // 131072 B

  hipMemsetAsync(d_out, 0, (size_t)out_size * sizeof(float), stream);

  init_kernel<<<(NROWS + 255) / 256, 256, 0, stream>>>(preds, inputs, in4, pr4, lu, lv);

  for (int it = 0; it < 50; ++it) {
    sink_phase<<<NROWS / 4, 256, 0, stream>>>(in4, pr4, lv, lu);  // lu update
    sink_phase<<<NROWS / 4, 256, 0, stream>>>(pr4, in4, lu, lv);  // lv update
  }

  assign_kernel<<<NROWS / 4, 256, 0, stream>>>(in4, pr4, lu, lv, perm4);
  knn_loss_kernel<<<NROWS / 4, 256, 0, stream>>>(in4, perm4, out);
}

// Round 3
// 1185.724 us; speedup vs baseline: 1.7189x; 1.1724x over previous
//
#include <hip/hip_runtime.h>
#include <stdint.h>

#define NB   4
#define NPTS 2048
#define NROWS (NB * NPTS)   // 8192
#define KNN  64
typedef unsigned long long u64;

// Sinkhorn runs in base-2 scaled domain: pot2 = pot * log2(e).
// K = 200*log2(e) (=(1/eps)*log2(e), eps=0.005)
#define NEG_SCALE_L2E (-288.53900817779268f)
#define TWO_SCALE_L2E (577.07801635558536f)

// ---------- helpers ----------

__device__ __forceinline__ float wave_sum(float v) {
#pragma unroll
  for (int o = 32; o >= 1; o >>= 1) v += __shfl_xor(v, o);
  return v;
}

// raw hardware exp2/log2 (used only inside Sinkhorn; consumer is a discrete
// argmax whose top-1/top-2 gap is orders of magnitude above the rounding noise)
__device__ __forceinline__ float fexp2(float x) {
  float r; asm("v_exp_f32 %0, %1" : "=v"(r) : "v"(x)); return r;
}
__device__ __forceinline__ float flog2(float x) {
  float r; asm("v_log_f32 %0, %1" : "=v"(r) : "v"(x)); return r;
}

__device__ __forceinline__ float sqdist(const float4 a, const float4 c) {
  float dot = a.x * c.x + a.y * c.y + a.z * c.z;
  float d   = a.w + c.w - 2.0f * dot;
  return fmaxf(d, 0.0f);
}

__device__ __forceinline__ uint32_t rotl32(uint32_t x, uint32_t d) {
  return (x << d) | (x >> (32u - d));
}

__device__ __forceinline__ int mbcnt64(u64 m) {
  return __builtin_amdgcn_mbcnt_hi((uint32_t)(m >> 32),
         __builtin_amdgcn_mbcnt_lo((uint32_t)m, 0));
}

__device__ __forceinline__ float2 lse_merge(float2 A, float2 B) {
  float nm = fmaxf(A.x, B.x);
  float s  = fmaf(A.y, fexp2(A.x - nm), B.y * fexp2(B.x - nm));
  return make_float2(nm, s);
}

// ---------- kernels ----------

__global__ __launch_bounds__(256) void init_kernel(
    const float* __restrict__ preds, const float* __restrict__ inputs,
    float4* __restrict__ in4, float4* __restrict__ pr4,
    float* __restrict__ lu, float* __restrict__ lv) {
  int i = blockIdx.x * 256 + threadIdx.x;
  if (i >= NROWS) return;
  float ax = inputs[3 * i], ay = inputs[3 * i + 1], az = inputs[3 * i + 2];
  in4[i] = make_float4(ax, ay, az, ax * ax + ay * ay + az * az);
  float px = preds[3 * i], py = preds[3 * i + 1], pz = preds[3 * i + 2];
  pr4[i] = make_float4(px, py, pz, px * px + py * py + pz * pz);
  lu[i] = 0.0f;
  lv[i] = 0.0f;
}

// One Sinkhorn half-step, LDS-broadcast layout.
// Block: 512 threads = 16 rows x 32 col-groups (64 cols each). Grid: 512.
// LDS columns staged as (x,y,z, fma(|c|^2, -K, pot)); per-row -K|a|^2 is
// added after the LSE (shift-invariance).
__global__ __launch_bounds__(512) void sink_phase(
    const float4* __restrict__ row_pts, const float4* __restrict__ col_pts,
    const float* __restrict__ pot_in, float* __restrict__ pot_out) {
  __shared__ float4 colv[NPTS];        // 32 KB
  __shared__ float2 part[32][16];      // 4 KB
  __shared__ float2 qpart[8][16];      // 1 KB
  int tid  = threadIdx.x;
  int rblk = blockIdx.x << 4;          // 16 rows per block
  int base = rblk & ~(NPTS - 1);

  for (int i = tid; i < NPTS; i += 512) {
    float4 c = col_pts[base + i];
    float  p = pot_in[base + i];
    colv[i] = make_float4(c.x, c.y, c.z, fmaf(c.w, NEG_SCALE_L2E, p));
  }
  __syncthreads();

  int row = tid & 15, g = tid >> 4;    // g in [0,32)
  float4 a = row_pts[rblk + row];
  int c0 = g << 6;
  float mx0 = -INFINITY, s0 = 0.0f, mx1 = -INFINITY, s1 = 0.0f;
#pragma unroll 8
  for (int c = 0; c < 64; c += 2) {
    float4 p0 = colv[c0 + c];
    float4 p1 = colv[c0 + c + 1];
    float dot0 = a.x * p0.x + a.y * p0.y + a.z * p0.z;
    float dot1 = a.x * p1.x + a.y * p1.y + a.z * p1.z;
    float y0 = fmaf(dot0, TWO_SCALE_L2E, p0.w);
    float y1 = fmaf(dot1, TWO_SCALE_L2E, p1.w);
    float n0 = fmaxf(mx0, y0);
    float n1 = fmaxf(mx1, y1);
    s0 = fmaf(s0, fexp2(mx0 - n0), fexp2(y0 - n0)); mx0 = n0;
    s1 = fmaf(s1, fexp2(mx1 - n1), fexp2(y1 - n1)); mx1 = n1;
  }
  part[g][row] = lse_merge(make_float2(mx0, s0), make_float2(mx1, s1));
  __syncthreads();

  if (tid < 128) {
    int r = tid & 15, q = tid >> 4;    // 8 quarters x 4 groups
    float2 P = part[4 * q][r];
#pragma unroll
    for (int k = 1; k < 4; ++k) P = lse_merge(P, part[4 * q + k][r]);
    qpart[q][r] = P;
  }
  __syncthreads();

  if (tid < 16) {
    float2 P = qpart[0][tid];
#pragma unroll
    for (int k = 1; k < 8; ++k) P = lse_merge(P, qpart[k][tid]);
    float aw = row_pts[rblk + tid].w;
    pot_out[rblk + tid] = -11.0f - (flog2(P.y) + P.x + NEG_SCALE_L2E * aw);
  }
}

// argmax_m(logK2 + lv2[m]) per row (lu[n] constant in m -> dropped).
// Same LDS-broadcast structure as sink_phase; first index wins ties.
__global__ __launch_bounds__(512) void assign_kernel(
    const float4* __restrict__ in4, const float4* __restrict__ pr4,
    const float* __restrict__ lv, float4* __restrict__ perm4) {
  __shared__ float4 colv[NPTS];        // 32 KB
  __shared__ u64 pmax[32][16];         // 4 KB
  __shared__ u64 qmax[8][16];          // 1 KB
  int tid  = threadIdx.x;
  int rblk = blockIdx.x << 4;
  int base = rblk & ~(NPTS - 1);

  for (int i = tid; i < NPTS; i += 512) {
    float4 c = pr4[base + i];
    float  p = lv[base + i];
    colv[i] = make_float4(c.x, c.y, c.z, fmaf(c.w, NEG_SCALE_L2E, p));
  }
  __syncthreads();

  int row = tid & 15, g = tid >> 4;
  float4 a = in4[rblk + row];
  int c0 = g << 6;
  u64 best = 0ull;
#pragma unroll 8
  for (int c = 0; c < 64; ++c) {
    float4 p = colv[c0 + c];
    float dot = a.x * p.x + a.y * p.y + a.z * p.z;
    float y   = fmaf(dot, TWO_SCALE_L2E, p.w);
    uint32_t u = __float_as_uint(y);
    u = (u & 0x80000000u) ? ~u : (u | 0x80000000u);   // order-preserving map
    int m = c0 + c;
    u64 pk = ((u64)u << 32) | (uint32_t)(2047 - m);   // ties -> min m
    best = (pk > best) ? pk : best;
  }
  pmax[g][row] = best;
  __syncthreads();

  if (tid < 128) {
    int r = tid & 15, q = tid >> 4;
    u64 B = pmax[4 * q][r];
#pragma unroll
    for (int k = 1; k < 4; ++k) { u64 x = pmax[4 * q + k][r]; B = (x > B) ? x : B; }
    qmax[q][r] = B;
  }
  __syncthreads();

  if (tid < 16) {
    u64 B = qmax[0][tid];
#pragma unroll
    for (int k = 1; k < 8; ++k) { u64 x = qmax[k][tid]; B = (x > B) ? x : B; }
    int m = 2047 - (int)(B & 0xFFFFFFFFu);
    perm4[rblk + tid] = pr4[base + m];
  }
}

// Per row (one wave, 4 waves/block): exact top-65 via bit-pattern binary
// search with ballot/popc counting (no shuffle chains), compaction via
// ballot+mbcnt, rank in LDS; then threefry mask + masked avg dist.
__global__ __launch_bounds__(256) void knn_loss_kernel(
    const float4* __restrict__ in4, const float4* __restrict__ perm4,
    float* __restrict__ out) {
  __shared__ u64 cand[4][96];
  __shared__ u64 sel[4][64];
  int wid  = threadIdx.x >> 6, lane = threadIdx.x & 63;
  int row  = blockIdx.x * 4 + wid;
  int base = row & ~(NPTS - 1);
  float4 a = in4[row];
  const float4* ip = in4 + base;

  uint32_t dvb[32];
#pragma unroll
  for (int t = 0; t < 32; ++t)
    dvb[t] = __float_as_uint(sqdist(a, ip[(t << 6) | lane]));

  // binary search for the 65th-smallest bit pattern (scalar-side counting)
  uint32_t lo = 0u, hi = 0x7F7FFFFFu;
  while (lo < hi) {
    uint32_t mid = lo + ((hi - lo) >> 1);
    int c = 0;
#pragma unroll
    for (int t = 0; t < 32; ++t) c += __popcll(__ballot(dvb[t] <= mid));
    if (c >= 65) hi = mid; else lo = mid + 1;
  }
  uint32_t T = lo;

  // compact candidates (bits <= T) via ballot + mbcnt offsets
  int pos = 0;
#pragma unroll
  for (int t = 0; t < 32; ++t) {
    bool pr = (dvb[t] <= T);
    u64 m = __ballot(pr);
    if (pr) {
      int idx = pos + mbcnt64(m);
      if (idx < 96) cand[wid][idx] = ((u64)dvb[t] << 32) | (uint32_t)((t << 6) | lane);
    }
    pos += __popcll(m);
  }
  int nc = pos < 96 ? pos : 96;

  // rank by (bits, idx); ranks 1..64 -> knn positions 0..63 (rank 0 = self)
  u64 mine0 = (lane < nc) ? cand[wid][lane] : ~0ull;
  u64 mine1 = (lane + 64 < nc) ? cand[wid][lane + 64] : ~0ull;
  int r0 = 0, r1 = 0;
  for (int j = 0; j < nc; ++j) {
    u64 cj = cand[wid][j];
    r0 += (cj < mine0) ? 1 : 0;
    r1 += (cj < mine1) ? 1 : 0;
  }
  if (lane < nc && r0 >= 1 && r0 <= 64) sel[wid][r0 - 1] = mine0;
  if (lane + 64 < nc && r1 >= 1 && r1 <= 64) sel[wid][r1 - 1] = mine1;
  u64 s = sel[wid][lane];
  float kd = __uint_as_float((uint32_t)(s >> 32));
  int   ki = (int)(s & 0xFFFFFFFFu);

  // prob (bit-exact float32 op order vs reference)
  const float C1 = (float)(0.05 * 0.05);
  const float C2 = (float)(2.0 * (0.5657 * 0.5657));
  const float C3 = (float)(0.5657 * 2.5066282746);
  float t2 = (kd / C1) / C2;
  float pr = expf(-t2) / C3;

  // jax.random.uniform(key(42), (4,2048,64)) : threefry2x32, bit-exact
  uint32_t gid = ((uint32_t)row << 6) | (uint32_t)lane;
  const uint32_t HALF = 262144u;
  bool lo2 = gid < HALF;
  uint32_t c0 = lo2 ? gid : (gid - HALF);
  uint32_t c1 = lo2 ? (gid + HALF) : gid;
  const uint32_t k0 = 0u, k1 = 42u;
  const uint32_t k2 = 0x1BD11BDAu ^ k0 ^ k1;
  uint32_t x0 = c0 + k0, x1 = c1 + k1;
#define TF_RND(rr) { x0 += x1; x1 = rotl32(x1, rr); x1 ^= x0; }
  TF_RND(13) TF_RND(15) TF_RND(26) TF_RND(6)
  x0 += k1; x1 += k2 + 1u;
  TF_RND(17) TF_RND(29) TF_RND(16) TF_RND(24)
  x0 += k2; x1 += k0 + 2u;
  TF_RND(13) TF_RND(15) TF_RND(26) TF_RND(6)
  x0 += k0; x1 += k1 + 3u;
  TF_RND(17) TF_RND(29) TF_RND(16) TF_RND(24)
  x0 += k1; x1 += k2 + 4u;
  TF_RND(13) TF_RND(15) TF_RND(26) TF_RND(6)
  x0 += k2; x1 += k0 + 5u;
#undef TF_RND
  uint32_t bits = lo2 ? x0 : x1;
  float u = __uint_as_float((bits >> 9) | 0x3F800000u) - 1.0f;

  bool msk = (u < pr);
  u64 bal = __ballot(msk);
  int cnt = __popcll(bal);
  if (cnt == 0 && lane == KNN - 1) msk = true;  // farthest fallback
  float num = (cnt == 0) ? 1.0f : (float)cnt;

  float4 nb = ip[ki];
  float4 pp = perm4[row];
  float dx = pp.x - nb.x, dy = pp.y - nb.y, dz = pp.z - nb.z;
  float dist = dx * dx + dy * dy + dz * dz;
  float contrib = msk ? dist : 0.0f;
  contrib = wave_sum(contrib);
  if (lane == 0) atomicAdd(out, contrib / num);
}

// ---------- launch ----------

extern "C" void kernel_launch(void* const* d_in, const int* in_sizes, int n_in,
                              void* d_out, int out_size, void* d_ws, size_t ws_size,
                              hipStream_t stream) {
  const float* preds  = (const float*)d_in[0];
  const float* inputs = (const float*)d_in[1];
  float* out = (float*)d_out;

  char* ws = (char*)d_ws;
  float4* in4   = (float4*)(ws);             // 131072 B
  float4* pr4   = (float4*)(ws + 131072);    // 131072 B
  float*  lu    = (float*)(ws + 262144);     // 32768 B (base-2 scaled)
  float*  lv    = (float*)(ws + 294912);     // 32768 B (base-2 scaled)
  float4* perm4 = (float4*)(ws + 327680);    // 131072 B

  hipMemsetAsync(d_out, 0, (size_t)out_size * sizeof(float), stream);

  init_kernel<<<(NROWS + 255) / 256, 256, 0, stream>>>(preds, inputs, in4, pr4, lu, lv);

  for (int it = 0; it < 50; ++it) {
    sink_phase<<<NROWS / 16, 512, 0, stream>>>(in4, pr4, lv, lu);  // lu update
    sink_phase<<<NROWS / 16, 512, 0, stream>>>(pr4, in4, lu, lv);  // lv update
  }

  assign_kernel<<<NROWS / 16, 512, 0, stream>>>(in4, pr4, lv, perm4);
  knn_loss_kernel<<<NROWS / 4, 256, 0, stream>>>(in4, perm4, out);
}